// Round 10
// baseline (32.254 us; speedup 1.0000x reference)
//
#include <hip/hip_runtime.h>

namespace {

constexpr int JN = 21;    // joints
constexpr int BN = 20;    // bones
constexpr int FR = 64;    // frames per block
constexpr int HT = 32;    // half-tile frames
constexpr int SPLIT0 = 36; // pose frames staged in chunk0 (36*63 floats, 16B-aligned split)

constexpr float F_F  = 512.0f;
constexpr float PX_F = 512.0f;
constexpr float PY_F = 288.0f;
constexpr float EPS_F = 1e-8f;

// weights folded with per-loss divisors
constexpr float WPROJ   = 0.25f / (2.0f * 21.0f);
constexpr float WLIFT   = 0.25f / (3.0f * 21.0f);
constexpr float WBONE   = 0.25f / 20.0f;
constexpr float WSMOOTH = 0.25f / (3.0f * 21.0f);

__device__ __forceinline__ double block_reduce(double val) {
    __shared__ double smem[16];
    const int lane = threadIdx.x & 63;
    const int wid  = threadIdx.x >> 6;
    #pragma unroll
    for (int off = 32; off > 0; off >>= 1)
        val += __shfl_down(val, off, 64);
    if (lane == 0) smem[wid] = val;
    __syncthreads();
    if (wid == 0) {
        const int nw = blockDim.x >> 6;
        val = (lane < nw) ? smem[lane] : 0.0;
        #pragma unroll
        for (int off = 32; off > 0; off >>= 1)
            val += __shfl_down(val, off, 64);
    }
    return val;
}

__global__ __launch_bounds__(256) void pose_loss_kernel(
    const float* __restrict__ pose3d,      // (W+1, 3, 21)
    const float* __restrict__ bone_2d,     // (W, 2, 21)
    const float* __restrict__ lift_dirs,   // (W, 3, 20)
    const float* __restrict__ R_drone,     // (W, 3, 3)
    const float* __restrict__ C_drone,     // (W, 3, 1)
    const float* __restrict__ bone_len,    // (20,)
    const float* __restrict__ R_cam,       // (3,3)
    float* __restrict__ partials,          // (gridDim.x,)
    int W)
{
    // pose 16.6 KB + M 3 KB -> ~19.7 KB -> 8 blocks/CU by LDS
    __shared__ alignas(16) float s_pose[(FR + 2) * 63 + 2];
    __shared__ alignas(16) float s_M[FR * 12];   // [M0..8, MC0..2] per frame, 48B stride

    const int tid = threadIdx.x;
    const int w0  = blockIdx.x * FR;
    const int nF  = min(FR, W - w0);
    const int nPoseF = min(FR + 2, W + 1 - w0);

    // coop float4 stage (both src and dst 16B-aligned by construction)
    auto stage4 = [&](float* dst, const float* src, int nfl) {
        const int n4 = nfl >> 2;
        const float4* s4 = (const float4*)src;
        float4* d4 = (float4*)dst;
        for (int i = tid; i < n4; i += 256) d4[i] = s4[i];
        for (int i = (n4 << 2) + tid; i < nfl; i += 256) dst[i] = src[i];
    };

    // per-frame M = R_cam @ Rd^T, MC = M @ C for frames [base, base+HT), lanes 0..31
    auto computeM = [&](int base) {
        const int f = base + tid;
        if (tid < HT && f < nF) {
            const float* Rd = R_drone + (size_t)(w0 + f) * 9;
            float rd[9];
            #pragma unroll
            for (int k = 0; k < 9; ++k) rd[k] = Rd[k];
            float rc[9];
            #pragma unroll
            for (int k = 0; k < 9; ++k) rc[k] = R_cam[k];   // uniform -> s_load
            float M[9];
            #pragma unroll
            for (int i = 0; i < 3; ++i)
                #pragma unroll
                for (int k = 0; k < 3; ++k)
                    M[i * 3 + k] = rc[i * 3 + 0] * rd[k * 3 + 0]
                                 + rc[i * 3 + 1] * rd[k * 3 + 1]
                                 + rc[i * 3 + 2] * rd[k * 3 + 2];
            const float* Cp = C_drone + (size_t)(w0 + f) * 3;
            const float C0 = Cp[0], C1 = Cp[1], C2 = Cp[2];
            #pragma unroll
            for (int k = 0; k < 9; ++k) s_M[f * 12 + k] = M[k];
            #pragma unroll
            for (int i = 0; i < 3; ++i)
                s_M[f * 12 + 9 + i] =
                    M[i * 3 + 0] * C0 + M[i * 3 + 1] * C1 + M[i * 3 + 2] * C2;
        }
    };

    float partial = 0.0f;

    // proj + bone + smooth per (wl, j); lift handled by dense f4 loop below
    auto item = [&](int wl, int j) {
        const int w = w0 + wl;

        const float* P1 = s_pose + (wl + 1) * 63;   // frame w+1
        const float p1x = P1[j];
        const float p1y = P1[JN + j];
        const float p1z = P1[2 * JN + j];

        // projection loss (M/MC via 3x ds_read_b128; streams bone_2d)
        {
            const float4 m0 = *(const float4*)(s_M + wl * 12);      // M[0..3]
            const float4 m1 = *(const float4*)(s_M + wl * 12 + 4);  // M[4..7]
            const float4 m2 = *(const float4*)(s_M + wl * 12 + 8);  // M8, MC0..2
            const float c0 = m0.x * p1x + m0.y * p1y + m0.z * p1z - m2.y;
            const float c1 = m0.w * p1x + m1.x * p1y + m1.y * p1z - m2.z;
            const float c2 = m1.z * p1x + m1.w * p1y + m2.x * p1z - m2.w;
            const float invz = 1.0f / c2;
            const float u = F_F * c0 * invz + PX_F;
            const float v = F_F * c1 * invz + PY_F;
            const float du = u - bone_2d[(size_t)w * 42 + j];
            const float dv = v - bone_2d[(size_t)w * 42 + JN + j];
            partial += WPROJ * (du * du + dv * dv);
        }

        // bone loss; bone_connections is statically (j+1, j)
        if (j < BN) {
            const int b0 = j + 1;
            const int b1 = j;
            const float blj = bone_len[j];
            {
                const float* P0 = s_pose + wl * 63;   // frame w
                const float bx = P0[b0]          - P0[b1];
                const float by = P0[JN + b0]     - P0[JN + b1];
                const float bz = P0[2 * JN + b0] - P0[2 * JN + b1];
                const float bl = bx * bx + by * by + bz * bz;
                const float e = blj - bl;
                partial += WBONE * (e * e);
            }
            if (w == W - 1) {                         // frame W == P1 here
                const float bx = P1[b0]          - P1[b1];
                const float by = P1[JN + b0]     - P1[JN + b1];
                const float bz = P1[2 * JN + b0] - P1[2 * JN + b1];
                const float bl = bx * bx + by * by + bz * bz;
                const float e = blj - bl;
                partial += WBONE * (e * e);
            }
        }

        // smoothness (t = w)
        if (w < W - 1) {
            const float* P0 = s_pose + wl * 63;
            const float* P2 = s_pose + (wl + 2) * 63;
            const float sx = P2[j]          - 2.0f * p1x + P0[j];
            const float sy = P2[JN + j]     - 2.0f * p1y + P0[JN + j];
            const float sz = P2[2 * JN + j] - 2.0f * p1z + P0[2 * JN + j];
            partial += WSMOOTH * (sx * sx + sy * sy + sz * sz);
        }
    };

    // dense lift compare: unit = (frame, coord c, 4-bone chunk k); one float4
    // global load per unit (lift frame stride 240B, rows of 20 -> always aligned,
    // never straddles a row). Bone vec + norm recomputed from LDS pose.
    auto liftCompare = [&](int wlBase, int wlEnd) {
        const int nUnits = (wlEnd - wlBase) * 15;     // 3 coords * 5 chunks
        for (int u = tid; u < nUnits; u += 256) {
            const int q15 = u / 15;
            const int rem = u - q15 * 15;
            const int wl  = wlBase + q15;
            const int c   = rem / 5;
            const int k   = rem - c * 5;
            const int jb  = 4 * k;

            const float* P1 = s_pose + (wl + 1) * 63;   // frame w+1
            float px[5], py[5], pz[5];
            #pragma unroll
            for (int t = 0; t < 5; ++t) {
                px[t] = P1[jb + t];
                py[t] = P1[JN + jb + t];
                pz[t] = P1[2 * JN + jb + t];
            }
            const float4 lv = *(const float4*)(
                lift_dirs + (size_t)(w0 + wl) * 60 + c * 20 + jb);
            const float lvArr[4] = {lv.x, lv.y, lv.z, lv.w};

            float acc = 0.0f;
            #pragma unroll
            for (int b = 0; b < 4; ++b) {
                const float bx = px[b + 1] - px[b];
                const float by = py[b + 1] - py[b];
                const float bz = pz[b + 1] - pz[b];
                const float inv = 1.0f / (sqrtf(bx * bx + by * by + bz * bz) + EPS_F);
                const float comp = (c == 0 ? bx : (c == 1 ? by : bz)) * inv;
                const float d = lvArr[b] - comp;
                acc += d * d;
            }
            partial += WLIFT * acc;
        }
    };

    // ---------------- prologue: stage chunk0 (frames [0,36)) + M for [0,32) ----------------
    {
        const int f1 = min(SPLIT0, nPoseF);
        stage4(s_pose, pose3d + (size_t)w0 * 63, f1 * 63);
        computeM(0);
    }
    __syncthreads();

    // ---------------- pipelined phase: stage chunk1 + M[32,64) overlapped with tile0 ----------------
    if (nPoseF > SPLIT0) {
        stage4(s_pose + SPLIT0 * 63, pose3d + ((size_t)w0 + SPLIT0) * 63,
               (nPoseF - SPLIT0) * 63);
    }
    computeM(HT);

    {
        const int nT0 = min(HT, nF);
        const int nItems0 = nT0 * JN;   // tile0: wl in [0,32)
        for (int it = tid; it < nItems0; it += 256) {
            const int wl = it / JN;
            const int j  = it - wl * JN;
            item(wl, j);
        }
        liftCompare(0, nT0);
    }
    __syncthreads();

    // ---------------- tile1: wl in [32, nF) ----------------
    if (nF > HT) {
        const int nItems1 = (nF - HT) * JN;
        for (int it = tid; it < nItems1; it += 256) {
            const int wl = HT + it / JN;
            const int j  = it - (it / JN) * JN;
            item(wl, j);
        }
        liftCompare(HT, nF);
    }

    const double bsum = block_reduce((double)partial);
    if (tid == 0) partials[blockIdx.x] = (float)bsum;
}

__global__ __launch_bounds__(256) void final_reduce_kernel(
    const float* __restrict__ partials, float* __restrict__ out, int n)
{
    double v = 0.0;
    for (int i = threadIdx.x; i < n; i += blockDim.x)
        v += (double)partials[i];
    v = block_reduce(v);
    if (threadIdx.x == 0) out[0] = (float)v;
}

}  // namespace

extern "C" void kernel_launch(void* const* d_in, const int* in_sizes, int n_in,
                              void* d_out, int out_size, void* d_ws, size_t ws_size,
                              hipStream_t stream) {
    const float* pose3d    = (const float*)d_in[0];
    const float* bone_2d   = (const float*)d_in[1];
    const float* lift_dirs = (const float*)d_in[2];
    const float* R_drone   = (const float*)d_in[3];
    const float* C_drone   = (const float*)d_in[4];
    const float* bone_len  = (const float*)d_in[5];
    const float* R_cam     = (const float*)d_in[6];
    float* out = (float*)d_out;
    float* partials = (float*)d_ws;

    const int W = in_sizes[3] / 9;       // R_drone is (W,3,3)
    const int grid = (W + FR - 1) / FR;  // 2048 for W=131072

    pose_loss_kernel<<<grid, 256, 0, stream>>>(
        pose3d, bone_2d, lift_dirs, R_drone, C_drone, bone_len, R_cam, partials, W);
    final_reduce_kernel<<<1, 256, 0, stream>>>(partials, out, grid);
}

// Round 11
// 28.906 us; speedup vs baseline: 1.1158x; 1.1158x over previous
//
#include <hip/hip_runtime.h>

namespace {

constexpr int JN = 21;    // joints
constexpr int BN = 20;    // bones
constexpr int FW = 16;    // frames per WAVE
constexpr int FR = 64;    // frames per block (4 waves)
constexpr int SLICE = FW + 2;          // pose frames per wave incl. halo
constexpr int SLICE_STRIDE = 1136;     // padded slice floats, 16B-aligned

constexpr float F_F  = 512.0f;
constexpr float PX_F = 512.0f;
constexpr float PY_F = 288.0f;
constexpr float EPS_F = 1e-8f;

// weights folded with per-loss divisors
constexpr float WPROJ   = 0.25f / (2.0f * 21.0f);
constexpr float WLIFT   = 0.25f / (3.0f * 21.0f);
constexpr float WBONE   = 0.25f / 20.0f;
constexpr float WSMOOTH = 0.25f / (3.0f * 21.0f);

__device__ __forceinline__ double block_reduce(double val) {
    __shared__ double smem[16];
    const int lane = threadIdx.x & 63;
    const int wid  = threadIdx.x >> 6;
    #pragma unroll
    for (int off = 32; off > 0; off >>= 1)
        val += __shfl_down(val, off, 64);
    if (lane == 0) smem[wid] = val;
    __syncthreads();
    if (wid == 0) {
        const int nw = blockDim.x >> 6;
        val = (lane < nw) ? smem[lane] : 0.0;
        #pragma unroll
        for (int off = 32; off > 0; off >>= 1)
            val += __shfl_down(val, off, 64);
    }
    return val;
}

__global__ __launch_bounds__(256) void pose_loss_kernel(
    const float* __restrict__ pose3d,      // (W+1, 3, 21)
    const float* __restrict__ bone_2d,     // (W, 2, 21)
    const float* __restrict__ lift_dirs,   // (W, 3, 20)
    const float* __restrict__ R_drone,     // (W, 3, 3)
    const float* __restrict__ C_drone,     // (W, 3, 1)
    const float* __restrict__ bone_len,    // (20,)
    const float* __restrict__ R_cam,       // (3,3)
    float* __restrict__ partials,          // (gridDim.x,)
    int W)
{
    // per-wave private regions: 4 x (1136 pose + 192 M) floats = 21.2 KB -> 7 blocks/CU
    __shared__ alignas(16) float s_pose[4][SLICE_STRIDE];
    __shared__ alignas(16) float s_M[4][FW * 12];   // [M0..8, MC0..2] per frame

    const int tid  = threadIdx.x;
    const int lane = tid & 63;
    const int wid  = tid >> 6;

    const int w0  = blockIdx.x * FR;
    const int fw0 = w0 + wid * FW;                  // this wave's first frame
    const int nFw = min(FW, W - fw0);               // frames this wave computes
    float* myPose = s_pose[wid];
    float* myM    = s_M[wid];

    float partial = 0.0f;

    if (nFw > 0) {
        // ---- wave-private stage: pose slice [fw0, fw0+18) (float4, dense) ----
        {
            const int nSliceF = min(SLICE, W + 1 - fw0);
            const int nfl = nSliceF * 63;
            const float* src = pose3d + (size_t)fw0 * 63;   // fw0*63 % 4 == 0
            const int n4 = nfl >> 2;
            const float4* s4 = (const float4*)src;
            float4* d4 = (float4*)myPose;
            for (int i = lane; i < n4; i += 64) d4[i] = s4[i];
            for (int i = (n4 << 2) + lane; i < nfl; i += 64) myPose[i] = src[i];
        }

        // ---- wave-private M: lanes 0..15, one frame each ----
        if (lane < FW && lane < nFw) {
            const float* Rd = R_drone + (size_t)(fw0 + lane) * 9;
            float rd[9];
            #pragma unroll
            for (int k = 0; k < 9; ++k) rd[k] = Rd[k];
            float rc[9];
            #pragma unroll
            for (int k = 0; k < 9; ++k) rc[k] = R_cam[k];   // uniform -> s_load
            float M[9];
            #pragma unroll
            for (int i = 0; i < 3; ++i)
                #pragma unroll
                for (int k = 0; k < 3; ++k)
                    M[i * 3 + k] = rc[i * 3 + 0] * rd[k * 3 + 0]
                                 + rc[i * 3 + 1] * rd[k * 3 + 1]
                                 + rc[i * 3 + 2] * rd[k * 3 + 2];
            const float* Cp = C_drone + (size_t)(fw0 + lane) * 3;
            const float C0 = Cp[0], C1 = Cp[1], C2 = Cp[2];
            #pragma unroll
            for (int k = 0; k < 9; ++k) myM[lane * 12 + k] = M[k];
            #pragma unroll
            for (int i = 0; i < 3; ++i)
                myM[lane * 12 + 9 + i] =
                    M[i * 3 + 0] * C0 + M[i * 3 + 1] * C1 + M[i * 3 + 2] * C2;
        }
        // wave-synchronous LDS: compiler inserts lgkmcnt waits on RAW; no barrier.

        // ---- per-item compute (wave-local frames) ----
        auto item = [&](int wl, int j) {
            const int w = fw0 + wl;

            const float* P1 = myPose + (wl + 1) * 63;   // frame w+1
            const float p1x = P1[j];
            const float p1y = P1[JN + j];
            const float p1z = P1[2 * JN + j];

            // projection loss (M/MC via 3x ds_read_b128; streams bone_2d)
            {
                const float4 m0 = *(const float4*)(myM + wl * 12);
                const float4 m1 = *(const float4*)(myM + wl * 12 + 4);
                const float4 m2 = *(const float4*)(myM + wl * 12 + 8);
                const float c0 = m0.x * p1x + m0.y * p1y + m0.z * p1z - m2.y;
                const float c1 = m0.w * p1x + m1.x * p1y + m1.y * p1z - m2.z;
                const float c2 = m1.z * p1x + m1.w * p1y + m2.x * p1z - m2.w;
                const float invz = 1.0f / c2;
                const float u = F_F * c0 * invz + PX_F;
                const float v = F_F * c1 * invz + PY_F;
                const float du = u - bone_2d[(size_t)w * 42 + j];
                const float dv = v - bone_2d[(size_t)w * 42 + JN + j];
                partial += WPROJ * (du * du + dv * dv);
            }

            // lift + bone losses; bone_connections is statically (j+1, j)
            if (j < BN) {
                const int b0 = j + 1;
                const int b1 = j;
                {
                    const float ax = P1[b0]          - P1[b1];
                    const float ay = P1[JN + b0]     - P1[JN + b1];
                    const float az = P1[2 * JN + b0] - P1[2 * JN + b1];
                    const float inv = 1.0f / (sqrtf(ax * ax + ay * ay + az * az) + EPS_F);
                    const float lx = lift_dirs[(size_t)w * 60 + j]          - ax * inv;
                    const float ly = lift_dirs[(size_t)w * 60 + BN + j]     - ay * inv;
                    const float lz = lift_dirs[(size_t)w * 60 + 2 * BN + j] - az * inv;
                    partial += WLIFT * (lx * lx + ly * ly + lz * lz);
                }
                const float blj = bone_len[j];
                {
                    const float* P0 = myPose + wl * 63;   // frame w
                    const float bx = P0[b0]          - P0[b1];
                    const float by = P0[JN + b0]     - P0[JN + b1];
                    const float bz = P0[2 * JN + b0] - P0[2 * JN + b1];
                    const float bl = bx * bx + by * by + bz * bz;
                    const float e = blj - bl;
                    partial += WBONE * (e * e);
                }
                if (w == W - 1) {                         // frame W == P1 here
                    const float bx = P1[b0]          - P1[b1];
                    const float by = P1[JN + b0]     - P1[JN + b1];
                    const float bz = P1[2 * JN + b0] - P1[2 * JN + b1];
                    const float bl = bx * bx + by * by + bz * bz;
                    const float e = blj - bl;
                    partial += WBONE * (e * e);
                }
            }

            // smoothness (t = w)
            if (w < W - 1) {
                const float* P0 = myPose + wl * 63;
                const float* P2 = myPose + (wl + 2) * 63;
                const float sx = P2[j]          - 2.0f * p1x + P0[j];
                const float sy = P2[JN + j]     - 2.0f * p1y + P0[JN + j];
                const float sz = P2[2 * JN + j] - 2.0f * p1z + P0[2 * JN + j];
                partial += WSMOOTH * (sx * sx + sy * sy + sz * sz);
            }
        };

        if (nFw == FW) {
            // 16*21 = 336 items = 5*64 + 16, statically unrolled
            #pragma unroll
            for (int k = 0; k < 5; ++k) {
                const int it = k * 64 + lane;
                item(it / JN, it - (it / JN) * JN);
            }
            if (lane < 16) {
                const int it = 5 * 64 + lane;   // 320..335
                item(it / JN, it - (it / JN) * JN);
            }
        } else {
            for (int it = lane; it < nFw * JN; it += 64)
                item(it / JN, it - (it / JN) * JN);
        }
    }

    const double bsum = block_reduce((double)partial);
    if (tid == 0) partials[blockIdx.x] = (float)bsum;
}

__global__ __launch_bounds__(256) void final_reduce_kernel(
    const float* __restrict__ partials, float* __restrict__ out, int n)
{
    double v = 0.0;
    for (int i = threadIdx.x; i < n; i += blockDim.x)
        v += (double)partials[i];
    v = block_reduce(v);
    if (threadIdx.x == 0) out[0] = (float)v;
}

}  // namespace

extern "C" void kernel_launch(void* const* d_in, const int* in_sizes, int n_in,
                              void* d_out, int out_size, void* d_ws, size_t ws_size,
                              hipStream_t stream) {
    const float* pose3d    = (const float*)d_in[0];
    const float* bone_2d   = (const float*)d_in[1];
    const float* lift_dirs = (const float*)d_in[2];
    const float* R_drone   = (const float*)d_in[3];
    const float* C_drone   = (const float*)d_in[4];
    const float* bone_len  = (const float*)d_in[5];
    const float* R_cam     = (const float*)d_in[6];
    float* out = (float*)d_out;
    float* partials = (float*)d_ws;

    const int W = in_sizes[3] / 9;       // R_drone is (W,3,3)
    const int grid = (W + FR - 1) / FR;  // 2048 for W=131072

    pose_loss_kernel<<<grid, 256, 0, stream>>>(
        pose3d, bone_2d, lift_dirs, R_drone, C_drone, bone_len, R_cam, partials, W);
    final_reduce_kernel<<<1, 256, 0, stream>>>(partials, out, grid);
}

// Round 12
// 28.279 us; speedup vs baseline: 1.1406x; 1.0222x over previous
//
#include <hip/hip_runtime.h>

namespace {

constexpr int JN = 21;    // joints
constexpr int BN = 20;    // bones
constexpr int FR = 64;    // frames per block

constexpr float F_F  = 512.0f;
constexpr float PX_F = 512.0f;
constexpr float PY_F = 288.0f;
constexpr float EPS_F = 1e-8f;

// weights folded with per-loss divisors
constexpr float WPROJ   = 0.25f / (2.0f * 21.0f);
constexpr float WLIFT   = 0.25f / (3.0f * 21.0f);
constexpr float WBONE   = 0.25f / 20.0f;
constexpr float WSMOOTH = 0.25f / (3.0f * 21.0f);

__device__ __forceinline__ double block_reduce(double val) {
    __shared__ double smem[16];
    const int lane = threadIdx.x & 63;
    const int wid  = threadIdx.x >> 6;
    #pragma unroll
    for (int off = 32; off > 0; off >>= 1)
        val += __shfl_down(val, off, 64);
    if (lane == 0) smem[wid] = val;
    __syncthreads();
    if (wid == 0) {
        const int nw = blockDim.x >> 6;
        val = (lane < nw) ? smem[lane] : 0.0;
        #pragma unroll
        for (int off = 32; off > 0; off >>= 1)
            val += __shfl_down(val, off, 64);
    }
    return val;
}

__global__ __launch_bounds__(256) void pose_loss_kernel(
    const float* __restrict__ pose3d,      // (W+1, 3, 21)
    const float* __restrict__ bone_2d,     // (W, 2, 21)
    const float* __restrict__ lift_dirs,   // (W, 3, 20)
    const float* __restrict__ R_drone,     // (W, 3, 3)
    const float* __restrict__ C_drone,     // (W, 3, 1)
    const float* __restrict__ bone_len,    // (20,)
    const float* __restrict__ R_cam,       // (3,3)
    float* __restrict__ partials,          // (gridDim.x,)
    int W)
{
    // pose 16.6 KB + M 3 KB -> ~19.7 KB -> 8 blocks/CU by LDS
    __shared__ alignas(16) float s_pose[(FR + 2) * 63 + 2];
    __shared__ alignas(16) float s_M[FR * 12];   // [M0..8, MC0..2] per frame, 48B stride

    const int tid = threadIdx.x;
    const int w0  = blockIdx.x * FR;
    const int nF  = min(FR, W - w0);
    const int nPoseF = min(FR + 2, W + 1 - w0);

    // ---------- stage pose (coalesced float4; base w0*63 is 16B-aligned) ----------
    {
        const float* src = pose3d + (size_t)w0 * 63;
        const int nfl = nPoseF * 63;
        const int n4 = nfl >> 2;
        const float4* s4 = (const float4*)src;
        float4* d4 = (float4*)s_pose;
        for (int i = tid; i < n4; i += 256) d4[i] = s4[i];
        for (int i = (n4 << 2) + tid; i < nfl; i += 256) s_pose[i] = src[i];
    }

    // ---------- per-frame M = R_cam @ Rd^T, MC = M @ C (threads 0..63) ----------
    if (tid < FR && tid < nF) {
        const float* Rd = R_drone + (size_t)(w0 + tid) * 9;
        float rd[9];
        #pragma unroll
        for (int k = 0; k < 9; ++k) rd[k] = Rd[k];
        float rc[9];
        #pragma unroll
        for (int k = 0; k < 9; ++k) rc[k] = R_cam[k];   // uniform -> s_load
        float M[9];
        #pragma unroll
        for (int i = 0; i < 3; ++i)
            #pragma unroll
            for (int k = 0; k < 3; ++k)
                M[i * 3 + k] = rc[i * 3 + 0] * rd[k * 3 + 0]
                             + rc[i * 3 + 1] * rd[k * 3 + 1]
                             + rc[i * 3 + 2] * rd[k * 3 + 2];
        const float* Cp = C_drone + (size_t)(w0 + tid) * 3;
        const float C0 = Cp[0], C1 = Cp[1], C2 = Cp[2];
        #pragma unroll
        for (int k = 0; k < 9; ++k) s_M[tid * 12 + k] = M[k];
        #pragma unroll
        for (int i = 0; i < 3; ++i)
            s_M[tid * 12 + 9 + i] =
                M[i * 3 + 0] * C0 + M[i * 3 + 1] * C1 + M[i * 3 + 2] * C2;
    }
    __syncthreads();

    float partial = 0.0f;

    // full chunk: frame wl, joints j0..j0+3 (j0 = 4k, k in 0..4)
    auto chunkFull = [&](int wl, int k) {
        const int w  = w0 + wl;
        const int j0 = 4 * k;
        const float* P1 = s_pose + (wl + 1) * 63 + j0;   // frame w+1
        const float* P0 = s_pose + wl * 63 + j0;         // frame w

        float p1x[5], p1y[5], p1z[5], p0x[5], p0y[5], p0z[5];
        #pragma unroll
        for (int t = 0; t < 5; ++t) {
            p1x[t] = P1[t]; p1y[t] = P1[21 + t]; p1z[t] = P1[42 + t];
            p0x[t] = P0[t]; p0y[t] = P0[21 + t]; p0z[t] = P0[42 + t];
        }

        const float4 m0 = *(const float4*)(s_M + wl * 12);      // M[0..3]
        const float4 m1 = *(const float4*)(s_M + wl * 12 + 4);  // M[4..7]
        const float4 m2 = *(const float4*)(s_M + wl * 12 + 8);  // M8, MC0..2

        // projection (streams bone_2d scalar; compiler pairs u-row loads)
        #pragma unroll
        for (int t = 0; t < 4; ++t) {
            const float c0 = m0.x * p1x[t] + m0.y * p1y[t] + m0.z * p1z[t] - m2.y;
            const float c1 = m0.w * p1x[t] + m1.x * p1y[t] + m1.y * p1z[t] - m2.z;
            const float c2 = m1.z * p1x[t] + m1.w * p1y[t] + m2.x * p1z[t] - m2.w;
            const float invz = 1.0f / c2;
            const float du = F_F * c0 * invz + PX_F - bone_2d[(size_t)w * 42 + j0 + t];
            const float dv = F_F * c1 * invz + PY_F - bone_2d[(size_t)w * 42 + 21 + j0 + t];
            partial += WPROJ * (du * du + dv * dv);
        }

        // lift: 3 aligned float4 global loads (frame stride 240B, offsets 16B)
        {
            const float4 lx = *(const float4*)(lift_dirs + (size_t)w * 60 + j0);
            const float4 ly = *(const float4*)(lift_dirs + (size_t)w * 60 + 20 + j0);
            const float4 lz = *(const float4*)(lift_dirs + (size_t)w * 60 + 40 + j0);
            const float lxa[4] = {lx.x, lx.y, lx.z, lx.w};
            const float lya[4] = {ly.x, ly.y, ly.z, ly.w};
            const float lza[4] = {lz.x, lz.y, lz.z, lz.w};
            #pragma unroll
            for (int t = 0; t < 4; ++t) {
                const float ax = p1x[t + 1] - p1x[t];
                const float ay = p1y[t + 1] - p1y[t];
                const float az = p1z[t + 1] - p1z[t];
                const float inv = 1.0f / (sqrtf(ax * ax + ay * ay + az * az) + EPS_F);
                const float dx = lxa[t] - ax * inv;
                const float dy = lya[t] - ay * inv;
                const float dz = lza[t] - az * inv;
                partial += WLIFT * (dx * dx + dy * dy + dz * dz);
            }
        }

        // bone (frame w) + frame-W edge
        {
            const float4 bl = *(const float4*)(bone_len + j0);
            const float bla[4] = {bl.x, bl.y, bl.z, bl.w};
            #pragma unroll
            for (int t = 0; t < 4; ++t) {
                const float bx = p0x[t + 1] - p0x[t];
                const float by = p0y[t + 1] - p0y[t];
                const float bz = p0z[t + 1] - p0z[t];
                const float e = bla[t] - (bx * bx + by * by + bz * bz);
                partial += WBONE * (e * e);
            }
            if (w == W - 1) {   // frame W == P1 here
                #pragma unroll
                for (int t = 0; t < 4; ++t) {
                    const float bx = p1x[t + 1] - p1x[t];
                    const float by = p1y[t + 1] - p1y[t];
                    const float bz = p1z[t + 1] - p1z[t];
                    const float e = bla[t] - (bx * bx + by * by + bz * bz);
                    partial += WBONE * (e * e);
                }
            }
        }

        // smooth (t = w), j0..j0+3
        if (w < W - 1) {
            const float* P2 = P0 + 126;   // frame w+2
            #pragma unroll
            for (int t = 0; t < 4; ++t) {
                const float sx = P2[t]      - 2.0f * p1x[t] + p0x[t];
                const float sy = P2[21 + t] - 2.0f * p1y[t] + p0y[t];
                const float sz = P2[42 + t] - 2.0f * p1z[t] + p0z[t];
                partial += WSMOOTH * (sx * sx + sy * sy + sz * sz);
            }
        }
    };

    // last chunk: joint j = 20 only (proj + smooth; no bone/lift)
    auto chunkLast = [&](int wl) {
        const int w = w0 + wl;
        const float* P1 = s_pose + (wl + 1) * 63 + 20;
        const float* P0 = s_pose + wl * 63 + 20;
        const float p1x = P1[0], p1y = P1[21], p1z = P1[42];

        const float4 m0 = *(const float4*)(s_M + wl * 12);
        const float4 m1 = *(const float4*)(s_M + wl * 12 + 4);
        const float4 m2 = *(const float4*)(s_M + wl * 12 + 8);
        const float c0 = m0.x * p1x + m0.y * p1y + m0.z * p1z - m2.y;
        const float c1 = m0.w * p1x + m1.x * p1y + m1.y * p1z - m2.z;
        const float c2 = m1.z * p1x + m1.w * p1y + m2.x * p1z - m2.w;
        const float invz = 1.0f / c2;
        const float du = F_F * c0 * invz + PX_F - bone_2d[(size_t)w * 42 + 20];
        const float dv = F_F * c1 * invz + PY_F - bone_2d[(size_t)w * 42 + 41];
        partial += WPROJ * (du * du + dv * dv);

        if (w < W - 1) {
            const float* P2 = P0 + 126;
            const float sx = P2[0]  - 2.0f * p1x + P0[0];
            const float sy = P2[21] - 2.0f * p1y + P0[21];
            const float sz = P2[42] - 2.0f * p1z + P0[42];
            partial += WSMOOTH * (sx * sx + sy * sy + sz * sz);
        }
    };

    auto doChunk = [&](int cid) {
        const int wl = cid / 6;
        const int k  = cid - wl * 6;
        if (k < 5) chunkFull(wl, k);
        else       chunkLast(wl);
    };

    if (nF == FR) {
        // 64 frames * 6 chunks = 384 = 256 + 128
        doChunk(tid);
        if (tid < FR * 6 - 256) doChunk(256 + tid);
    } else {
        for (int c = tid; c < nF * 6; c += 256) doChunk(c);
    }

    const double bsum = block_reduce((double)partial);
    if (tid == 0) partials[blockIdx.x] = (float)bsum;
}

__global__ __launch_bounds__(256) void final_reduce_kernel(
    const float* __restrict__ partials, float* __restrict__ out, int n)
{
    double v = 0.0;
    for (int i = threadIdx.x; i < n; i += blockDim.x)
        v += (double)partials[i];
    v = block_reduce(v);
    if (threadIdx.x == 0) out[0] = (float)v;
}

}  // namespace

extern "C" void kernel_launch(void* const* d_in, const int* in_sizes, int n_in,
                              void* d_out, int out_size, void* d_ws, size_t ws_size,
                              hipStream_t stream) {
    const float* pose3d    = (const float*)d_in[0];
    const float* bone_2d   = (const float*)d_in[1];
    const float* lift_dirs = (const float*)d_in[2];
    const float* R_drone   = (const float*)d_in[3];
    const float* C_drone   = (const float*)d_in[4];
    const float* bone_len  = (const float*)d_in[5];
    const float* R_cam     = (const float*)d_in[6];
    float* out = (float*)d_out;
    float* partials = (float*)d_ws;

    const int W = in_sizes[3] / 9;       // R_drone is (W,3,3)
    const int grid = (W + FR - 1) / FR;  // 2048 for W=131072

    pose_loss_kernel<<<grid, 256, 0, stream>>>(
        pose3d, bone_2d, lift_dirs, R_drone, C_drone, bone_len, R_cam, partials, W);
    final_reduce_kernel<<<1, 256, 0, stream>>>(partials, out, grid);
}

// Round 13
// 23.703 us; speedup vs baseline: 1.3608x; 1.1931x over previous
//
#include <hip/hip_runtime.h>

namespace {

typedef float f2 __attribute__((ext_vector_type(2)));

constexpr int JN = 21;    // joints
constexpr int FR = 64;    // frames per block

constexpr float F_F  = 512.0f;
constexpr float PX_F = 512.0f;
constexpr float PY_F = 288.0f;
constexpr float EPS_F = 1e-8f;

// weights folded with per-loss divisors
constexpr float WPROJ   = 0.25f / (2.0f * 21.0f);
constexpr float WLIFT   = 0.25f / (3.0f * 21.0f);
constexpr float WBONE   = 0.25f / 20.0f;
constexpr float WSMOOTH = 0.25f / (3.0f * 21.0f);

__device__ __forceinline__ double block_reduce(double val) {
    __shared__ double smem[16];
    const int lane = threadIdx.x & 63;
    const int wid  = threadIdx.x >> 6;
    #pragma unroll
    for (int off = 32; off > 0; off >>= 1)
        val += __shfl_down(val, off, 64);
    if (lane == 0) smem[wid] = val;
    __syncthreads();
    if (wid == 0) {
        const int nw = blockDim.x >> 6;
        val = (lane < nw) ? smem[lane] : 0.0;
        #pragma unroll
        for (int off = 32; off > 0; off >>= 1)
            val += __shfl_down(val, off, 64);
    }
    return val;
}

__global__ __launch_bounds__(256) void pose_loss_kernel(
    const float* __restrict__ pose3d,      // (W+1, 3, 21)
    const float* __restrict__ bone_2d,     // (W, 2, 21)
    const float* __restrict__ lift_dirs,   // (W, 3, 20)
    const float* __restrict__ R_drone,     // (W, 3, 3)
    const float* __restrict__ C_drone,     // (W, 3, 1)
    const float* __restrict__ bone_len,    // (20,)
    const float* __restrict__ R_cam,       // (3,3)
    float* __restrict__ partials,          // (gridDim.x,)
    int W)
{
    // pose 16.6 KB + M 3 KB -> ~19.7 KB -> 8 blocks/CU by LDS
    __shared__ alignas(16) float s_pose[(FR + 2) * 63 + 2];
    // permuted per-frame row (stride 12):
    // [0]={M0} [1]={M3} [2]={M1} [3]={M4} [4]={M2} [5]={M5} [6]=MC0 [7]=MC1
    // [8]=M6 [9]=M7 [10]=M8 [11]=MC2
    __shared__ alignas(16) float s_M[FR * 12];

    const int tid = threadIdx.x;
    const int w0  = blockIdx.x * FR;
    const int nF  = min(FR, W - w0);
    const int nPoseF = min(FR + 2, W + 1 - w0);

    // ---------- stage pose (coalesced float4; base w0*63 is 16B-aligned) ----------
    {
        const float* src = pose3d + (size_t)w0 * 63;
        const int nfl = nPoseF * 63;
        const int n4 = nfl >> 2;
        const float4* s4 = (const float4*)src;
        float4* d4 = (float4*)s_pose;
        for (int i = tid; i < n4; i += 256) d4[i] = s4[i];
        for (int i = (n4 << 2) + tid; i < nfl; i += 256) s_pose[i] = src[i];
    }

    // ---------- per-frame M = R_cam @ Rd^T, MC = M @ C (threads 0..nF-1) ----------
    if (tid < nF) {
        const float* Rd = R_drone + (size_t)(w0 + tid) * 9;
        float rd[9];
        #pragma unroll
        for (int k = 0; k < 9; ++k) rd[k] = Rd[k];
        float rc[9];
        #pragma unroll
        for (int k = 0; k < 9; ++k) rc[k] = R_cam[k];   // uniform -> s_load
        float M[9];
        #pragma unroll
        for (int i = 0; i < 3; ++i)
            #pragma unroll
            for (int k = 0; k < 3; ++k)
                M[i * 3 + k] = rc[i * 3 + 0] * rd[k * 3 + 0]
                             + rc[i * 3 + 1] * rd[k * 3 + 1]
                             + rc[i * 3 + 2] * rd[k * 3 + 2];
        const float* Cp = C_drone + (size_t)(w0 + tid) * 3;
        const float C0 = Cp[0], C1 = Cp[1], C2 = Cp[2];
        float MC[3];
        #pragma unroll
        for (int i = 0; i < 3; ++i)
            MC[i] = M[i * 3 + 0] * C0 + M[i * 3 + 1] * C1 + M[i * 3 + 2] * C2;
        float* mb = s_M + tid * 12;
        mb[0] = M[0]; mb[1] = M[3];
        mb[2] = M[1]; mb[3] = M[4];
        mb[4] = M[2]; mb[5] = M[5];
        mb[6] = MC[0]; mb[7] = MC[1];
        mb[8] = M[6]; mb[9] = M[7]; mb[10] = M[8]; mb[11] = MC[2];
    }
    __syncthreads();

    float partial = 0.0f;

    // fixed-j mapping: 252 active threads = 12 frame-groups x 21 joints
    if (tid < 252) {
        const int j = tid % 21;
        const int g = tid / 21;
        const bool hasBone = (j < 20);
        const float blj = hasBone ? bone_len[j] : 0.0f;

        for (int wl = g; wl < nF; wl += 12) {
            const int w = w0 + wl;
            const float* P0 = s_pose + wl * 63;
            const float* P1 = P0 + 63;
            const float* mb = s_M + wl * 12;

            const float x0 = P1[j], y0 = P1[21 + j], z0 = P1[42 + j];

            // ---- projection (pk math; fast rcp) ----
            {
                const f2 A = *(const f2*)(mb + 0);
                const f2 B = *(const f2*)(mb + 2);
                const f2 C = *(const f2*)(mb + 4);
                const f2 D = *(const f2*)(mb + 6);
                const float4 E = *(const float4*)(mb + 8);   // M6,M7,M8,MC2
                f2 c01 = A * x0 + B * y0 + C * z0 - D;
                const float c2 = E.x * x0 + E.y * y0 + E.z * z0 - E.w;
                const float invz = __builtin_amdgcn_rcpf(c2);
                f2 uv = c01 * (F_F * invz) + (f2){PX_F, PY_F};
                const f2 b2 = { bone_2d[(size_t)w * 42 + j],
                                bone_2d[(size_t)w * 42 + 21 + j] };
                const f2 duv = uv - b2;
                partial += WPROJ * (duv.x * duv.x + duv.y * duv.y);
            }

            if (hasBone) {
                // ---- lift (frame w+1 bone direction) ----
                const float ax = P1[j + 1]      - x0;
                const float ay = P1[21 + j + 1] - y0;
                const float az = P1[42 + j + 1] - z0;
                const float q  = ax * ax + ay * ay + az * az;
                const float inv = __builtin_amdgcn_rcpf(
                                      __builtin_amdgcn_sqrtf(q) + EPS_F);
                const float lx = lift_dirs[(size_t)w * 60 + j]      - ax * inv;
                const float ly = lift_dirs[(size_t)w * 60 + 20 + j] - ay * inv;
                const float lz = lift_dirs[(size_t)w * 60 + 40 + j] - az * inv;
                partial += WLIFT * (lx * lx + ly * ly + lz * lz);

                // ---- bone (frame w) ----
                const float bx = P0[j + 1]      - P0[j];
                const float by = P0[21 + j + 1] - P0[21 + j];
                const float bz = P0[42 + j + 1] - P0[42 + j];
                const float e = blj - (bx * bx + by * by + bz * bz);
                partial += WBONE * (e * e);
                if (w == W - 1) {              // frame W == P1 here; |bone|^2 == q
                    const float e2 = blj - q;
                    partial += WBONE * (e2 * e2);
                }
            }

            // ---- smoothness (t = w) ----
            if (w < W - 1) {
                const float* P2 = P0 + 126;
                const float sx = P2[j]      - 2.0f * x0 + P0[j];
                const float sy = P2[21 + j] - 2.0f * y0 + P0[21 + j];
                const float sz = P2[42 + j] - 2.0f * z0 + P0[42 + j];
                partial += WSMOOTH * (sx * sx + sy * sy + sz * sz);
            }
        }
    }

    const double bsum = block_reduce((double)partial);
    if (tid == 0) partials[blockIdx.x] = (float)bsum;
}

__global__ __launch_bounds__(256) void final_reduce_kernel(
    const float* __restrict__ partials, float* __restrict__ out, int n)
{
    double v = 0.0;
    const int n4 = n >> 2;
    const float4* p4 = (const float4*)partials;
    for (int i = threadIdx.x; i < n4; i += blockDim.x) {
        const float4 x = p4[i];
        v += (double)x.x + (double)x.y + (double)x.z + (double)x.w;
    }
    for (int i = (n4 << 2) + threadIdx.x; i < n; i += blockDim.x)
        v += (double)partials[i];
    v = block_reduce(v);
    if (threadIdx.x == 0) out[0] = (float)v;
}

}  // namespace

extern "C" void kernel_launch(void* const* d_in, const int* in_sizes, int n_in,
                              void* d_out, int out_size, void* d_ws, size_t ws_size,
                              hipStream_t stream) {
    const float* pose3d    = (const float*)d_in[0];
    const float* bone_2d   = (const float*)d_in[1];
    const float* lift_dirs = (const float*)d_in[2];
    const float* R_drone   = (const float*)d_in[3];
    const float* C_drone   = (const float*)d_in[4];
    const float* bone_len  = (const float*)d_in[5];
    const float* R_cam     = (const float*)d_in[6];
    float* out = (float*)d_out;
    float* partials = (float*)d_ws;

    const int W = in_sizes[3] / 9;       // R_drone is (W,3,3)
    const int grid = (W + FR - 1) / FR;  // 2048 for W=131072

    pose_loss_kernel<<<grid, 256, 0, stream>>>(
        pose3d, bone_2d, lift_dirs, R_drone, C_drone, bone_len, R_cam, partials, W);
    final_reduce_kernel<<<1, 256, 0, stream>>>(partials, out, grid);
}